// Round 8
// baseline (148.373 us; speedup 1.0000x reference)
//
#include <hip/hip_runtime.h>

#define NT 512

constexpr int L0 = 8192;
constexpr int N1 = 4099;   // (8192+7)>>1
constexpr int N2 = 2053;   // (4099+7)>>1
constexpr int N3 = 1030;   // (2053+7)>>1
constexpr int N4 = 518;    // (1030+7)>>1
constexpr int ROW_OUT = N4 + N4 + N3 + N2 + N1;  // 8218
constexpr int OFF_A4 = 0;
constexpr int OFF_D4 = 518;
constexpr int OFF_D3 = 1036;
constexpr int OFF_D2 = 2066;
constexpr int OFF_D1 = 4119;

// Halo SoA stride (slots per coefficient lane).
constexpr int HS = 520;

// 4-byte-aligned vector types: out-row offsets (4119+8t etc.) are only
// dword-aligned. Plain (non-nontemporal) stores: L2 write-combines the
// wave's dense 1KB runs; nt bypassed L2 and cost +6MB of partial-sector
// HBM writes in round 7.
typedef float f4u __attribute__((ext_vector_type(4), aligned(4)));
typedef float f2u __attribute__((ext_vector_type(2), aligned(4)));

// lo[i] = sum_j GLO[j] * xsym(2i-6+j)   (GLO = pywt db4 rec_lo = dec_lo reversed)
constexpr float GLO[8] = {
    0.23037781330885523f,  0.7148465705525415f,   0.6308807679295904f,
   -0.02798376941698385f, -0.18703481171888114f,  0.030841381835986965f,
    0.032883011666982945f, -0.010597401784997278f };
// hi[i] = sum_j GHI[j] * xsym(2i-6+j)
constexpr float GHI[8] = {
   -0.010597401784997278f, -0.032883011666982945f, 0.030841381835986965f,
    0.18703481171888114f,  -0.02798376941698385f,  -0.6308807679295904f,
    0.7148465705525415f,   -0.23037781330885523f };

// Load x window [16t-8, 16t+16) into registers (all loads issued together).
__device__ __forceinline__ void load_xw(const float* __restrict__ xr, int t,
                                        float* __restrict__ xw)
{
    if (t > 0) {
        const float4* p = (const float4*)(xr + 16 * t - 8);
        float4 v0 = p[0], v1 = p[1], v2 = p[2], v3 = p[3], v4 = p[4], v5 = p[5];
        xw[0] = v0.x;  xw[1] = v0.y;  xw[2] = v0.z;  xw[3] = v0.w;
        xw[4] = v1.x;  xw[5] = v1.y;  xw[6] = v1.z;  xw[7] = v1.w;
        xw[8] = v2.x;  xw[9] = v2.y;  xw[10] = v2.z; xw[11] = v2.w;
        xw[12] = v3.x; xw[13] = v3.y; xw[14] = v3.z; xw[15] = v3.w;
        xw[16] = v4.x; xw[17] = v4.y; xw[18] = v4.z; xw[19] = v4.w;
        xw[20] = v5.x; xw[21] = v5.y; xw[22] = v5.z; xw[23] = v5.w;
    } else {
        const float4* p = (const float4*)xr;
        float4 v0 = p[0], v1 = p[1], v2 = p[2], v3 = p[3];
        xw[8] = v0.x;  xw[9] = v0.y;  xw[10] = v0.z; xw[11] = v0.w;
        xw[12] = v1.x; xw[13] = v1.y; xw[14] = v1.z; xw[15] = v1.w;
        xw[16] = v2.x; xw[17] = v2.y; xw[18] = v2.z; xw[19] = v2.w;
        xw[20] = v3.x; xw[21] = v3.y; xw[22] = v3.z; xw[23] = v3.w;
#pragma unroll
        for (int k = 0; k < 8; ++k) xw[k] = xw[15 - k];   // xsym(k-8) = x[7-k]
    }
}

// Round-7 register cascade (verified bit-exact), now 2 rows per block:
// grid = 1024 = 4 blocks/CU x 256 CU -> the whole grid is ONE co-resident
// generation (no ramp/drain between generations). Row 1's x-loads are
// prefetch-issued during row 0's L3 phase (~2000 cycles ahead of first use).
__global__ __launch_bounds__(NT, 8) void wavedec4_db4(const float* __restrict__ x,
                                                      float* __restrict__ out)
{
    __shared__ float hA[8 * HS];   // 16640 B : cA1 SoA, later cA3 [g&1][g>>1]
    __shared__ float hB[4 * HS];   //  8320 B : cA2 SoA [m*HS + t]
    const int t = threadIdx.x;
    const size_t row0 = (size_t)blockIdx.x * 2;

    float xw[24];
    load_xw(x + row0 * L0, t, xw);

#pragma unroll
    for (int r = 0; r < 2; ++r) {
        float* __restrict__ outr = out + (row0 + r) * (size_t)ROW_OUT;
        if (r == 1) __syncthreads();   // row0 L4 hA reads done before row1 hA writes

        // ---- L1: outputs i = 8t+m, taps xw[2m+2+j] ----
        float lo1[8], hi1[8];
#pragma unroll
        for (int m = 0; m < 8; ++m) {
            float l = 0.f, h = 0.f;
#pragma unroll
            for (int j = 0; j < 8; ++j) {
                float v = xw[2 * m + 2 + j];
                l = fmaf(GLO[j], v, l);
                h = fmaf(GHI[j], v, h);
            }
            lo1[m] = l;
            hi1[m] = h;
            hA[m * HS + t] = l;
        }
        {   // direct coalesced cD1 stores: lane holds cD1[8t..8t+7]
            f4u a = { hi1[0], hi1[1], hi1[2], hi1[3] };
            f4u b = { hi1[4], hi1[5], hi1[6], hi1[7] };
            *(f4u*)(outr + OFF_D1 + 8 * t) = a;
            *(f4u*)(outr + OFF_D1 + 8 * t + 4) = b;
        }
        if (t == NT - 1) {   // L1 tail i = 4096..4098, entirely from xw registers
#pragma unroll
            for (int e = 0; e < 3; ++e) {
                const int i = 4096 + e;
                float l = 0.f, h = 0.f;
#pragma unroll
                for (int j = 0; j < 8; ++j) {
                    int q = 2 * i - 6 + j;                       // 8186..8202
                    int idx = ((q <= 8191) ? q : (16383 - q)) - 8168;
                    float v = xw[idx];
                    l = fmaf(GLO[j], v, l);
                    h = fmaf(GHI[j], v, h);
                }
                outr[OFF_D1 + i] = h;
                hA[(i & 7) * HS + (i >> 3)] = l;
            }
        }
        __syncthreads();

        // ---- L2: outputs j = 4t+m, taps w2[2m+j'] where w2[k] = cA1[8t-6+k] ----
        float w2[14];
#pragma unroll
        for (int k = 0; k < 6; ++k) {
            int g = 8 * t - 6 + k;
            if (g < 0) g = -1 - g;                 // front reflection (t=0 only)
            w2[k] = hA[(g & 7) * HS + (g >> 3)];
        }
#pragma unroll
        for (int m = 0; m < 8; ++m) w2[6 + m] = lo1[m];
        float lo2[4], hi2[4];
#pragma unroll
        for (int m = 0; m < 4; ++m) {
            float l = 0.f, h = 0.f;
#pragma unroll
            for (int j = 0; j < 8; ++j) {
                float v = w2[2 * m + j];
                l = fmaf(GLO[j], v, l);
                h = fmaf(GHI[j], v, h);
            }
            lo2[m] = l;
            hi2[m] = h;
            hB[m * HS + t] = l;
        }
        {   // direct coalesced cD2 store: lane holds cD2[4t..4t+3]
            f4u a = { hi2[0], hi2[1], hi2[2], hi2[3] };
            *(f4u*)(outr + OFF_D2 + 4 * t) = a;
        }
        if (t < 5) {    // L2 tail: j = 2048..2052 from published cA1 (+tail reflection)
            const int jj = 2048 + t;
            float l = 0.f, h = 0.f;
#pragma unroll
            for (int j = 0; j < 8; ++j) {
                int g = 2 * jj - 6 + j;
                if (g > 4098) g = 8197 - g;        // reflect at N1
                float v = hA[(g & 7) * HS + (g >> 3)];
                l = fmaf(GLO[j], v, l);
                h = fmaf(GHI[j], v, h);
            }
            outr[OFF_D2 + jj] = h;
            hB[(jj & 3) * HS + (jj >> 2)] = l;
        }
        __syncthreads();

        // ---- prefetch row1's x window: issue early so HBM latency hides
        //      under L3 + L4 compute of row 0 ----
        if (r == 0) load_xw(x + (row0 + 1) * L0, t, xw);

        // ---- L3: outputs j = 2t+m, taps w3[2m+j'] where w3[k] = cA2[4t-6+k] ----
        float w3[10];
#pragma unroll
        for (int k = 0; k < 6; ++k) {
            int g = 4 * t - 6 + k;
            if (g < 0) g = -1 - g;
            w3[k] = hB[(g & 3) * HS + (g >> 2)];
        }
#pragma unroll
        for (int m = 0; m < 4; ++m) w3[6 + m] = lo2[m];
        float lo3[2], hi3[2];
#pragma unroll
        for (int m = 0; m < 2; ++m) {
            float l = 0.f, h = 0.f;
#pragma unroll
            for (int j = 0; j < 8; ++j) {
                float v = w3[2 * m + j];
                l = fmaf(GLO[j], v, l);
                h = fmaf(GHI[j], v, h);
            }
            lo3[m] = l;
            hi3[m] = h;
            hA[m * HS + t] = l;                    // cA3 pair view: (2t+m)&1=m, >>1=t
        }
        {   // direct coalesced cD3 store: lane holds cD3[2t..2t+1]
            f2u a = { hi3[0], hi3[1] };
            *(f2u*)(outr + OFF_D3 + 2 * t) = a;
        }
        if (t < 6) {    // L3 tail: j = 1024..1029 from published cA2 (+reflection)
            const int jj = 1024 + t;
            float l = 0.f, h = 0.f;
#pragma unroll
            for (int j = 0; j < 8; ++j) {
                int g = 2 * jj - 6 + j;
                if (g > 2052) g = 4105 - g;        // reflect at N2
                float v = hB[(g & 3) * HS + (g >> 2)];
                l = fmaf(GLO[j], v, l);
                h = fmaf(GHI[j], v, h);
            }
            outr[OFF_D3 + jj] = h;
            hA[(jj & 1) * HS + (jj >> 1)] = l;
        }
        __syncthreads();

        // ---- L4: output j = t, taps w4[j'] where w4[k] = cA3[2t-6+k] ----
        float w4[8];
#pragma unroll
        for (int k = 0; k < 6; ++k) {
            int g = 2 * t - 6 + k;
            if (g < 0) g = -1 - g;
            w4[k] = hA[(g & 1) * HS + (g >> 1)];
        }
        w4[6] = lo3[0];
        w4[7] = lo3[1];
        {
            float l = 0.f, h = 0.f;
#pragma unroll
            for (int j = 0; j < 8; ++j) {
                float v = w4[j];
                l = fmaf(GLO[j], v, l);
                h = fmaf(GHI[j], v, h);
            }
            outr[OFF_A4 + t] = l;      // lane-consecutive (coalesced)
            outr[OFF_D4 + t] = h;
        }
        if (t < 6) {    // L4 tail: j = 512..517 from published cA3 (+reflection)
            const int jj = 512 + t;
            float l = 0.f, h = 0.f;
#pragma unroll
            for (int j = 0; j < 8; ++j) {
                int g = 2 * jj - 6 + j;
                if (g > 1029) g = 2059 - g;        // reflect at N3
                float v = hA[(g & 1) * HS + (g >> 1)];
                l = fmaf(GLO[j], v, l);
                h = fmaf(GHI[j], v, h);
            }
            outr[OFF_A4 + jj] = l;
            outr[OFF_D4 + jj] = h;
        }
    }
}

extern "C" void kernel_launch(void* const* d_in, const int* in_sizes, int n_in,
                              void* d_out, int out_size, void* d_ws, size_t ws_size,
                              hipStream_t stream) {
    const float* x = (const float*)d_in[0];
    float* out = (float*)d_out;
    const int rows = in_sizes[0] / L0;  // 64*32 = 2048
    wavedec4_db4<<<dim3(rows / 2), dim3(NT), 0, stream>>>(x, out);
}

// Round 9
// 114.272 us; speedup vs baseline: 1.2984x; 1.2984x over previous
//
#include <hip/hip_runtime.h>

#define NT 512

constexpr int L0 = 8192;
constexpr int N1 = 4099;   // (8192+7)>>1
constexpr int N2 = 2053;   // (4099+7)>>1
constexpr int N3 = 1030;   // (2053+7)>>1
constexpr int N4 = 518;    // (1030+7)>>1
constexpr int ROW_OUT = N4 + N4 + N3 + N2 + N1;  // 8218
constexpr int OFF_A4 = 0;
constexpr int OFF_D4 = 518;
constexpr int OFF_D3 = 1036;
constexpr int OFF_D2 = 2066;
constexpr int OFF_D1 = 4119;

// Halo SoA stride (slots per coefficient lane).
constexpr int HS = 520;

// 4-byte-aligned vector types: out-row offsets (4119+8t etc.) are only
// dword-aligned. Plain stores (NOT nontemporal): L2 write-combines the
// wave's dense 1KB runs; nt bypassed L2 and cost +6MB partial-sector HBM
// writes in round 7. Round 8's 163MB write blowup was launch-bounds VGPR
// spill from the cross-phase register prefetch — do NOT hold extra state
// across phases in this structure.
typedef float f4u __attribute__((ext_vector_type(4), aligned(4)));
typedef float f2u __attribute__((ext_vector_type(2), aligned(4)));

// lo[i] = sum_j GLO[j] * xsym(2i-6+j)   (GLO = pywt db4 rec_lo = dec_lo reversed)
constexpr float GLO[8] = {
    0.23037781330885523f,  0.7148465705525415f,   0.6308807679295904f,
   -0.02798376941698385f, -0.18703481171888114f,  0.030841381835986965f,
    0.032883011666982945f, -0.010597401784997278f };
// hi[i] = sum_j GHI[j] * xsym(2i-6+j)
constexpr float GHI[8] = {
   -0.010597401784997278f, -0.032883011666982945f, 0.030841381835986965f,
    0.18703481171888114f,  -0.02798376941698385f,  -0.6308807679295904f,
    0.7148465705525415f,   -0.23037781330885523f };

// Round-7 register cascade (verified bit-exact, best measured: 27.5us),
// with plain stores instead of nontemporal. One row per block, 3 barriers.
__global__ __launch_bounds__(NT, 8) void wavedec4_db4(const float* __restrict__ x,
                                                      float* __restrict__ out)
{
    __shared__ float hA[8 * HS];   // 16640 B : cA1 SoA, later cA3 [g&1][g>>1]
    __shared__ float hB[4 * HS];   //  8320 B : cA2 SoA [m*HS + t]
    const int t = threadIdx.x;
    const float* __restrict__ xr = x + blockIdx.x * (size_t)L0;
    float* __restrict__ outr = out + blockIdx.x * (size_t)ROW_OUT;

    // ---- load x window [16t-8, 16t+16) into registers, all loads up front ----
    float xw[24];
    if (t > 0) {
        const float4* p = (const float4*)(xr + 16 * t - 8);
        float4 v0 = p[0], v1 = p[1], v2 = p[2], v3 = p[3], v4 = p[4], v5 = p[5];
        xw[0] = v0.x;  xw[1] = v0.y;  xw[2] = v0.z;  xw[3] = v0.w;
        xw[4] = v1.x;  xw[5] = v1.y;  xw[6] = v1.z;  xw[7] = v1.w;
        xw[8] = v2.x;  xw[9] = v2.y;  xw[10] = v2.z; xw[11] = v2.w;
        xw[12] = v3.x; xw[13] = v3.y; xw[14] = v3.z; xw[15] = v3.w;
        xw[16] = v4.x; xw[17] = v4.y; xw[18] = v4.z; xw[19] = v4.w;
        xw[20] = v5.x; xw[21] = v5.y; xw[22] = v5.z; xw[23] = v5.w;
    } else {
        const float4* p = (const float4*)xr;
        float4 v0 = p[0], v1 = p[1], v2 = p[2], v3 = p[3];
        xw[8] = v0.x;  xw[9] = v0.y;  xw[10] = v0.z; xw[11] = v0.w;
        xw[12] = v1.x; xw[13] = v1.y; xw[14] = v1.z; xw[15] = v1.w;
        xw[16] = v2.x; xw[17] = v2.y; xw[18] = v2.z; xw[19] = v2.w;
        xw[20] = v3.x; xw[21] = v3.y; xw[22] = v3.z; xw[23] = v3.w;
#pragma unroll
        for (int k = 0; k < 8; ++k) xw[k] = xw[15 - k];   // xsym(k-8) = x[7-k]
    }

    // ---- L1: outputs i = 8t+m, taps xw[2m+2+j] ----
    float lo1[8], hi1[8];
#pragma unroll
    for (int m = 0; m < 8; ++m) {
        float l = 0.f, h = 0.f;
#pragma unroll
        for (int j = 0; j < 8; ++j) {
            float v = xw[2 * m + 2 + j];
            l = fmaf(GLO[j], v, l);
            h = fmaf(GHI[j], v, h);
        }
        lo1[m] = l;
        hi1[m] = h;
        hA[m * HS + t] = l;
    }
    {   // direct coalesced cD1 stores: lane holds cD1[8t..8t+7]
        f4u a = { hi1[0], hi1[1], hi1[2], hi1[3] };
        f4u b = { hi1[4], hi1[5], hi1[6], hi1[7] };
        *(f4u*)(outr + OFF_D1 + 8 * t) = a;
        *(f4u*)(outr + OFF_D1 + 8 * t + 4) = b;
    }
    if (t == NT - 1) {   // L1 tail i = 4096..4098, entirely from xw registers
#pragma unroll
        for (int e = 0; e < 3; ++e) {
            const int i = 4096 + e;
            float l = 0.f, h = 0.f;
#pragma unroll
            for (int j = 0; j < 8; ++j) {
                int q = 2 * i - 6 + j;                       // 8186..8202
                int idx = ((q <= 8191) ? q : (16383 - q)) - 8168;
                float v = xw[idx];
                l = fmaf(GLO[j], v, l);
                h = fmaf(GHI[j], v, h);
            }
            outr[OFF_D1 + i] = h;
            hA[(i & 7) * HS + (i >> 3)] = l;
        }
    }
    __syncthreads();

    // ---- L2: outputs j = 4t+m, taps w2[2m+j'] where w2[k] = cA1[8t-6+k] ----
    float w2[14];
#pragma unroll
    for (int k = 0; k < 6; ++k) {
        int g = 8 * t - 6 + k;
        if (g < 0) g = -1 - g;                 // front reflection (t=0 only)
        w2[k] = hA[(g & 7) * HS + (g >> 3)];
    }
#pragma unroll
    for (int m = 0; m < 8; ++m) w2[6 + m] = lo1[m];
    float lo2[4], hi2[4];
#pragma unroll
    for (int m = 0; m < 4; ++m) {
        float l = 0.f, h = 0.f;
#pragma unroll
        for (int j = 0; j < 8; ++j) {
            float v = w2[2 * m + j];
            l = fmaf(GLO[j], v, l);
            h = fmaf(GHI[j], v, h);
        }
        lo2[m] = l;
        hi2[m] = h;
        hB[m * HS + t] = l;
    }
    {   // direct coalesced cD2 store: lane holds cD2[4t..4t+3]
        f4u a = { hi2[0], hi2[1], hi2[2], hi2[3] };
        *(f4u*)(outr + OFF_D2 + 4 * t) = a;
    }
    if (t < 5) {    // L2 tail: j = 2048..2052 from published cA1 (+tail reflection)
        const int jj = 2048 + t;
        float l = 0.f, h = 0.f;
#pragma unroll
        for (int j = 0; j < 8; ++j) {
            int g = 2 * jj - 6 + j;
            if (g > 4098) g = 8197 - g;        // reflect at N1
            float v = hA[(g & 7) * HS + (g >> 3)];
            l = fmaf(GLO[j], v, l);
            h = fmaf(GHI[j], v, h);
        }
        outr[OFF_D2 + jj] = h;
        hB[(jj & 3) * HS + (jj >> 2)] = l;
    }
    __syncthreads();

    // ---- L3: outputs j = 2t+m, taps w3[2m+j'] where w3[k] = cA2[4t-6+k] ----
    float w3[10];
#pragma unroll
    for (int k = 0; k < 6; ++k) {
        int g = 4 * t - 6 + k;
        if (g < 0) g = -1 - g;
        w3[k] = hB[(g & 3) * HS + (g >> 2)];
    }
#pragma unroll
    for (int m = 0; m < 4; ++m) w3[6 + m] = lo2[m];
    float lo3[2], hi3[2];
#pragma unroll
    for (int m = 0; m < 2; ++m) {
        float l = 0.f, h = 0.f;
#pragma unroll
        for (int j = 0; j < 8; ++j) {
            float v = w3[2 * m + j];
            l = fmaf(GLO[j], v, l);
            h = fmaf(GHI[j], v, h);
        }
        lo3[m] = l;
        hi3[m] = h;
        hA[m * HS + t] = l;                    // cA3 pair view: (2t+m)&1=m, >>1=t
    }
    {   // direct coalesced cD3 store: lane holds cD3[2t..2t+1]
        f2u a = { hi3[0], hi3[1] };
        *(f2u*)(outr + OFF_D3 + 2 * t) = a;
    }
    if (t < 6) {    // L3 tail: j = 1024..1029 from published cA2 (+reflection)
        const int jj = 1024 + t;
        float l = 0.f, h = 0.f;
#pragma unroll
        for (int j = 0; j < 8; ++j) {
            int g = 2 * jj - 6 + j;
            if (g > 2052) g = 4105 - g;        // reflect at N2
            float v = hB[(g & 3) * HS + (g >> 2)];
            l = fmaf(GLO[j], v, l);
            h = fmaf(GHI[j], v, h);
        }
        outr[OFF_D3 + jj] = h;
        hA[(jj & 1) * HS + (jj >> 1)] = l;
    }
    __syncthreads();

    // ---- L4: output j = t, taps w4[j'] where w4[k] = cA3[2t-6+k] ----
    float w4[8];
#pragma unroll
    for (int k = 0; k < 6; ++k) {
        int g = 2 * t - 6 + k;
        if (g < 0) g = -1 - g;
        w4[k] = hA[(g & 1) * HS + (g >> 1)];
    }
    w4[6] = lo3[0];
    w4[7] = lo3[1];
    {
        float l = 0.f, h = 0.f;
#pragma unroll
        for (int j = 0; j < 8; ++j) {
            float v = w4[j];
            l = fmaf(GLO[j], v, l);
            h = fmaf(GHI[j], v, h);
        }
        outr[OFF_A4 + t] = l;      // lane-consecutive (coalesced)
        outr[OFF_D4 + t] = h;
    }
    if (t < 6) {    // L4 tail: j = 512..517 from published cA3 (+reflection)
        const int jj = 512 + t;
        float l = 0.f, h = 0.f;
#pragma unroll
        for (int j = 0; j < 8; ++j) {
            int g = 2 * jj - 6 + j;
            if (g > 1029) g = 2059 - g;        // reflect at N3
            float v = hA[(g & 1) * HS + (g >> 1)];
            l = fmaf(GLO[j], v, l);
            h = fmaf(GHI[j], v, h);
        }
        outr[OFF_A4 + jj] = l;
        outr[OFF_D4 + jj] = h;
    }
}

extern "C" void kernel_launch(void* const* d_in, const int* in_sizes, int n_in,
                              void* d_out, int out_size, void* d_ws, size_t ws_size,
                              hipStream_t stream) {
    const float* x = (const float*)d_in[0];
    float* out = (float*)d_out;
    const int rows = in_sizes[0] / L0;  // 64*32 = 2048
    wavedec4_db4<<<dim3(rows), dim3(NT), 0, stream>>>(x, out);
}